// Round 5
// baseline (72.437 us; speedup 1.0000x reference)
//
#include <hip/hip_runtime.h>
#include <cmath>

#define NGRAPHS 1024
#define ZDIM 16
#define NB 10
#define SHD 16
#define FEAT 2560   // 16 z * 10 b * 16 sh
#define HCHUNK 64          // per-half chunk (typ. half-segment ~25; loop handles overflow)
#define CSTRIDE 92         // 64 + 27 pad; 92 % 32 == 28 -> 16 rows pair 2-way on banks (free)
#define WIN 1536           // windowed-search width: 3 elements per thread at 512 threads

// 512-thread block per graph; half h = tid>>8 accumulates over half the nodes
// into its own staging buffers (s_stage[h]); halves combine IN-BLOCK via LDS
// (no fences / cross-block traffic). 1024 blocks x 8 waves = 32 waves/CU
// (100% occupancy) vs the old 16 — this round tests the latency-hiding
// hypothesis (r3/r4 showed the kernel issues ~2-3us of work but runs ~15us).
//
// Per half: nodes bucketed by radial-basis ib at staging (within-ONE-wave
// ballot ranking: counts known to all lanes -> 2 barriers/chunk, not 3);
// inner loop = 9 compile-time-ib mini-loops, 3x ds_read_b128 + 8 v_fmac per
// 4 nodes, branch-free. Only shA/shB pad columns are zeroed per chunk (xT
// stale values are finite after the one-time zero; x*0 contributions vanish).
__global__ __launch_bounds__(512) void yfe_kernel(
    const float* __restrict__ xin,
    const float* __restrict__ pos,
    const int* __restrict__ batch,
    float* __restrict__ out,
    int n_nodes)
{
    const int g = blockIdx.x;
    const int tid = threadIdx.x;
    const int n = n_nodes;
    const int h = tid >> 8;        // half index 0/1
    const int t = tid & 255;       // thread-in-half

    __shared__ int s_red[18];
    __shared__ int s_cum[2][10];
    __shared__ __align__(16) float s_stage[2][3][SHD][CSTRIDE];  // [half][xT|shA|shB]

    // one-time zero: guarantees xT stale reads are always finite (LDS power-on
    // garbage can be NaN; 0*NaN = NaN). Ordered before staging by search barriers.
    {
        const float4 z4 = make_float4(0.f, 0.f, 0.f, 0.f);
        float4* z = (float4*)s_stage;
        for (int i = tid; i < (int)(sizeof(s_stage) / 16); i += 512) z[i] = z4;
    }

    // ---- windowed segment search (batch sorted; 512 threads x 3 probes) ----
    int start, end;
    bool window_ok = (n >= WIN);
    if (window_ok) {
        const int ctr = (int)(((long long)(2 * g + 1) * n) >> 11);  // (g+0.5)*n/1024
        int p0 = ctr - WIN / 2;
        if (p0 < 0) p0 = 0;
        if (p0 > n - WIN) p0 = n - WIN;
        int vals[3];
#pragma unroll
        for (int k = 0; k < 3; ++k) vals[k] = batch[p0 + tid + k * 512];
        int wA = 0, wB = 0;
#pragma unroll
        for (int k = 0; k < 3; ++k) {
            wA += __popcll(__ballot(vals[k] < g));
            wB += __popcll(__ballot(vals[k] < g + 1));
        }
        if ((tid & 63) == 0) {
            s_red[tid >> 6]     = wA;   // identical across lanes of the wave
            s_red[8 + (tid >> 6)] = wB;
        }
        if (tid == 0)   s_red[16] = vals[0];   // batch[p0]
        if (tid == 511) s_red[17] = vals[2];   // batch[p0 + WIN - 1]
        __syncthreads();
        int KA = 0, KB = 0;
#pragma unroll
        for (int q = 0; q < 8; ++q) { KA += s_red[q]; KB += s_red[8 + q]; }
        start = p0 + KA;
        end   = p0 + KB;
        const bool left_ok  = (p0 == 0) || (s_red[16] < g);
        const bool right_ok = (p0 + WIN == n) || (s_red[17] >= g + 1);
        window_ok = left_ok && right_ok;      // block-uniform
        __syncthreads();                      // s_red reused below (fallback)
    }
    if (!window_ok) {
        // ---- exact fallback: 2-level strided search at 512 threads ----
        {
            const int p1 = (int)(((long long)tid * n) >> 9);
            const int v = batch[p1];
            const unsigned long long balA = __ballot(v < g);
            const unsigned long long balB = __ballot(v < g + 1);
            if ((tid & 63) == 0) {
                s_red[tid >> 6]       = __popcll(balA);
                s_red[8 + (tid >> 6)] = __popcll(balB);
            }
        }
        __syncthreads();
        int KA = 0, KB = 0;
#pragma unroll
        for (int q = 0; q < 8; ++q) { KA += s_red[q]; KB += s_red[8 + q]; }
        const int loA = (KA == 0) ? 0 : (int)(((long long)(KA - 1) * n) >> 9) + 1;
        const int hiA = (KA == 512) ? n : (int)(((long long)KA * n) >> 9);
        const int loB = (KB == 0) ? 0 : (int)(((long long)(KB - 1) * n) >> 9) + 1;
        const int hiB = (KB == 512) ? n : (int)(((long long)KB * n) >> 9);
        __syncthreads();
        // level 2: window width <= ceil(n/512) < 512 threads
        const int pA = loA + tid;
        const int pB = loB + tid;
        const int prA = (pA < hiA) ? (batch[pA] < g) : 0;
        const int prB = (pB < hiB) ? (batch[pB] < g + 1) : 0;
        const unsigned long long balA = __ballot(prA);
        const unsigned long long balB = __ballot(prB);
        if ((tid & 63) == 0) {
            s_red[tid >> 6]       = __popcll(balA);
            s_red[8 + (tid >> 6)] = __popcll(balB);
        }
        __syncthreads();
        int sA = 0, sB = 0;
#pragma unroll
        for (int q = 0; q < 8; ++q) { sA += s_red[q]; sB += s_red[8 + q]; }
        start = loA + sA;
        end   = loB + sB;
        __syncthreads();
    }
    const int cnt = end - start;
    const int mid = start + ((cnt + 1) >> 1);
    const int hstart = h ? mid : start;
    const int hend   = h ? end : mid;
    // both halves iterate the SAME chunk count (block-uniform barriers);
    // half A is the larger half, so this covers both. Empty chunks stage nothing.
    const int nchunks = (((cnt + 1) >> 1) + HCHUNK - 1) >> 6;

    float (*xT )[CSTRIDE] = s_stage[h][0];
    float (*shA)[CSTRIDE] = s_stage[h][1];
    float (*shB)[CSTRIDE] = s_stage[h][2];

    const int zi  = t >> 4;
    const int shi = t & 15;
    const int l   = (shi >= 9) ? 3 : (shi >= 4) ? 2 : (shi >= 1) ? 1 : 0;
    const int m   = shi - l * l;
    const int w   = 2 * l + 1;
    const int off = (l == 0) ? 0 : (l == 1) ? 160 : (l == 2) ? 640 : 1440;
    const int fbase = off + zi * 10 * w + m;   // out index for b=0; +b*w

    float acc[NB];
#pragma unroll
    for (int b = 0; b < NB; ++b) acc[b] = 0.0f;

    // c = SMOOTH_FINITE_C * e^2 * sqrt(NBASIS)
    const float CB = (float)(1.14136 * 7.389056098930650 * 3.1622776601683795);

    for (int ic = 0; ic < nchunks; ++ic) {
        const int nb0 = hstart + (ic << 6);
        int nrem = hend - nb0;
        nrem = (nrem < 0) ? 0 : ((nrem > HCHUNK) ? HCHUNK : nrem);
        __syncthreads();   // protect previous iteration's LDS reads (both halves)

        if (t < 64) {      // staging wave of this half (one full wave)
            int my_ib = 9;                       // 9 = no bucket (inactive lane)
            float bvA = 0.0f, bvB = 0.0f;
            float sh[SHD];
            float4 xr0, xr1, xr2, xr3;
            if (t < nrem) {
                const int node = nb0 + t;
                const float px = pos[node * 3 + 0];
                const float py = pos[node * 3 + 1];
                const float pz = pos[node * 3 + 2];
                const float4* xp = (const float4*)(xin + (size_t)node * ZDIM);
                xr0 = xp[0]; xr1 = xp[1]; xr2 = xp[2]; xr3 = xp[3];  // fly under sh compute
                const float r2 = px * px + py * py + pz * pz;
                const float rinv = rsqrtf(r2);
                const float X = px * rinv, Y = py * rinv, Z = pz * rinv;
                const float x2 = X * X, y2 = Y * Y, z2 = Z * Z;
                const float x2z2 = x2 + z2;
                const float s3  = 1.7320508075688772f;
                const float s5  = 2.2360679774997896f;
                const float s7  = 2.6457513110645907f;
                const float s15 = 3.8729833462074170f;
                const float c42_6  = 1.0801234497346435f;   // sqrt(42)/6
                const float c168_8 = 1.6201851746019651f;   // sqrt(168)/8
                const float sh2_0 = s15 * X * Z;
                const float sh2_1 = s15 * X * Y;
                const float sh2_2 = s5 * (y2 - 0.5f * x2z2);
                const float sh2_3 = s15 * Y * Z;
                const float sh2_4 = 0.5f * s15 * (z2 - x2);
                sh[0]  = 1.0f;
                sh[1]  = s3 * X;
                sh[2]  = s3 * Y;
                sh[3]  = s3 * Z;
                sh[4]  = sh2_0;
                sh[5]  = sh2_1;
                sh[6]  = sh2_2;
                sh[7]  = sh2_3;
                sh[8]  = sh2_4;
                sh[9]  = c42_6 * (sh2_0 * Z + sh2_4 * X);
                sh[10] = s7 * sh2_0 * Y;
                sh[11] = c168_8 * (4.0f * y2 - x2z2) * X;
                sh[12] = 0.5f * s7 * Y * (2.0f * y2 - 3.0f * x2z2);
                sh[13] = c168_8 * Z * (4.0f * y2 - x2z2);
                sh[14] = s7 * sh2_4 * Y;
                sh[15] = c42_6 * (sh2_4 * Z - sh2_0 * X);
                // radial basis: t'=1.1*d; active b in (t'-2, t') -> {ib, ib+1}
                const float d = r2 * rinv;
                const float tt = d * 1.1f;
                int ib = (int)floorf(tt) - 1;
                ib = min(max(ib, 0), 8);
                {
                    const float u1 = tt - (float)ib, u2 = (float)(ib + 2) - tt;
                    if (u1 > 0.0f && u2 > 0.0f) bvA = CB * __expf(-1.0f / u1 - 1.0f / u2);
                    const float v1 = tt - (float)(ib + 1), v2 = (float)(ib + 3) - tt;
                    if (v1 > 0.0f && v2 > 0.0f) bvB = CB * __expf(-1.0f / v1 - 1.0f / v2);
                }
                my_ib = ib;
            }
            // within-wave ballot ranking: every lane learns all 9 counts
            const unsigned long long lt = (1ull << (unsigned)t) - 1ull;   // t < 64
            int rank = 0, cv[9];
#pragma unroll
            for (int v = 0; v < 9; ++v) {
                const unsigned long long bal = __ballot(my_ib == v);
                if (my_ib == v) rank = __popcll(bal & lt);
                cv[v] = __popcll(bal);
            }
            int cum[10];
            cum[0] = 0;
#pragma unroll
            for (int v = 0; v < 9; ++v) cum[v + 1] = cum[v] + ((cv[v] + 3) & ~3);
            // pad-only zeroing of shA/shB (<=3 cols/bucket); lanes: col parity by
            // t>>5, array by (t>>4)&1, row by t&15 -> 32 lanes cover one column.
#pragma unroll
            for (int v = 0; v < 9; ++v) {
                const int base = cum[v] + cv[v];
                const int pe   = cum[v + 1];
                for (int c = base + (t >> 5); c < pe; c += 2) {
                    if (((t >> 4) & 1) == 0) shA[t & 15][c] = 0.0f;
                    else                     shB[t & 15][c] = 0.0f;
                }
            }
            // stage into bucket-permuted columns (disjoint from pad columns)
            if (t < nrem) {
                int dest = rank;
#pragma unroll
                for (int v = 0; v < 9; ++v)
                    dest += (v < my_ib) ? ((cv[v] + 3) & ~3) : 0;
#pragma unroll
                for (int k = 0; k < SHD; ++k) {
                    shA[k][dest] = sh[k] * bvA;
                    shB[k][dest] = sh[k] * bvB;
                }
                xT[ 0][dest] = xr0.x; xT[ 1][dest] = xr0.y;
                xT[ 2][dest] = xr0.z; xT[ 3][dest] = xr0.w;
                xT[ 4][dest] = xr1.x; xT[ 5][dest] = xr1.y;
                xT[ 6][dest] = xr1.z; xT[ 7][dest] = xr1.w;
                xT[ 8][dest] = xr2.x; xT[ 9][dest] = xr2.y;
                xT[10][dest] = xr2.z; xT[11][dest] = xr2.w;
                xT[12][dest] = xr3.x; xT[13][dest] = xr3.y;
                xT[14][dest] = xr3.z; xT[15][dest] = xr3.w;
            }
            if (t == 0) {   // publish padded bucket starts for the other 3 waves
                s_cum[h][0] = cum[0]; s_cum[h][1] = cum[1]; s_cum[h][2] = cum[2];
                s_cum[h][3] = cum[3]; s_cum[h][4] = cum[4]; s_cum[h][5] = cum[5];
                s_cum[h][6] = cum[6]; s_cum[h][7] = cum[7]; s_cum[h][8] = cum[8];
                s_cum[h][9] = cum[9];
            }
        }
        __syncthreads();   // staged data + cum visible

        int cum[10];
#pragma unroll
        for (int v = 0; v < 10; ++v) cum[v] = s_cum[h][v];

        // ---- branch-free inner loop: 9 compile-time-ib bucket loops ----
#pragma unroll
        for (int v = 0; v < 9; ++v) {
#pragma unroll 2
            for (int c = cum[v]; c < cum[v + 1]; c += 4) {
                const float4 xv = *(const float4*)&xT[zi][c];
                const float4 sA = *(const float4*)&shA[shi][c];
                const float4 sB = *(const float4*)&shB[shi][c];
                acc[v] = fmaf(xv.w, sA.w, fmaf(xv.z, sA.z,
                         fmaf(xv.y, sA.y, fmaf(xv.x, sA.x, acc[v]))));
                acc[v + 1] = fmaf(xv.w, sB.w, fmaf(xv.z, sB.z,
                             fmaf(xv.y, sB.y, fmaf(xv.x, sB.x, acc[v + 1]))));
            }
        }
    }

    // ---- in-block combine: half B publishes to LDS, half A merges + scales ----
    __syncthreads();   // all inner-loop LDS reads complete (both halves)
    const float scale = 1.0f / (float)max(cnt, 1);
    float* comb = &s_stage[1][0][0][0];     // 4416 floats >= FEAT, half-1 area dead
    if (h == 1) {
#pragma unroll
        for (int b = 0; b < NB; ++b) comb[fbase + b * w] = acc[b];
    }
    __syncthreads();
    float* outbuf = &s_stage[0][0][0][0];   // half-0 area dead; holds final row
    if (h == 0) {
#pragma unroll
        for (int b = 0; b < NB; ++b)
            outbuf[fbase + b * w] = (acc[b] + comb[fbase + b * w]) * scale;
    }
    __syncthreads();
    float4* og4 = (float4*)(out + (size_t)g * FEAT);
    const float4* ob4 = (const float4*)outbuf;
    for (int i = tid; i < FEAT / 4; i += 512) og4[i] = ob4[i];
}

extern "C" void kernel_launch(void* const* d_in, const int* in_sizes, int n_in,
                              void* d_out, int out_size, void* d_ws, size_t ws_size,
                              hipStream_t stream) {
    const float* x   = (const float*)d_in[0];
    const float* pos = (const float*)d_in[1];
    const int* batch = (const int*)d_in[2];
    float* out = (float*)d_out;
    const int n_nodes = in_sizes[2];

    hipLaunchKernelGGL(yfe_kernel, dim3(NGRAPHS), dim3(512), 0, stream,
                       x, pos, batch, out, n_nodes);
}

// Round 6
// 66.636 us; speedup vs baseline: 1.0871x; 1.0871x over previous
//
#include <hip/hip_runtime.h>
#include <cmath>

#define NGRAPHS 1024
#define ZDIM 16
#define NB 10
#define SHD 16
#define FEAT 2560   // 16 z * 10 b * 16 sh
#define CHUNK 96           // max nodes staged per iteration (typ. segment ~49; loop handles overflow)
#define CSTRIDE 132        // >= CHUNK + 9*3 pad; 132 % 32 == 4 -> worst 2-way bank conflict (free)
#define WIN 1536           // windowed-search width: 6 elements per thread

// One block per graph. Thread ownership: tid -> (z = tid>>4, sh = tid&15).
// Radial basis is 2-sparse: only b in {ib, ib+1} nonzero per node, ib node-uniform.
// Nodes are BUCKETED BY ib at staging time; inner loop is 9 compile-time-ib
// mini-loops: 3x ds_read_b128 + 8 v_fmac per 4 nodes, no branches in the body.
//
// Session history (measured): r0 71.1 -> windowed search 70.25 -> ib-bucket
// debranch 65.74 -> staging trims 65.59 (this version). Structural
// alternatives measured and rejected: cross-block fenced combine (+245us),
// 512-thread/32-wave occupancy split (+6.8us). This is the best-known state.
__global__ __launch_bounds__(256) void yfe_kernel(
    const float* __restrict__ xin,
    const float* __restrict__ pos,
    const int* __restrict__ batch,
    float* __restrict__ out,
    int n_nodes)
{
    const int g = blockIdx.x;
    const int tid = threadIdx.x;
    const int n = n_nodes;

    __shared__ int s_red[12];
    __shared__ int s_bcnt[9];        // bucket counters (LDS atomics)
    __shared__ __align__(16) float s_xT[ZDIM][CSTRIDE];
    __shared__ __align__(16) float s_shA[SHD][CSTRIDE];   // sh[m] * bvA, bucket-permuted
    __shared__ __align__(16) float s_shB[SHD][CSTRIDE];   // sh[m] * bvB, bucket-permuted
    __shared__ __align__(16) float s_out[FEAT];

    if (tid < 9) s_bcnt[tid] = 0;    // visible after the first in-loop barrier

    int start, end;
    bool window_ok = (n >= WIN);
    if (window_ok) {
        // ---- windowed local search: one cold round, block-private lines ----
        const int ctr = (int)(((long long)(2 * g + 1) * n) >> 11);  // (g+0.5)*n/1024
        int p0 = ctr - WIN / 2;
        if (p0 < 0) p0 = 0;
        if (p0 > n - WIN) p0 = n - WIN;
        int vals[6];
#pragma unroll
        for (int k = 0; k < 6; ++k) vals[k] = batch[p0 + tid + k * 256];
        int wA = 0, wB = 0;
#pragma unroll
        for (int k = 0; k < 6; ++k) {
            wA += __popcll(__ballot(vals[k] < g));
            wB += __popcll(__ballot(vals[k] < g + 1));
        }
        if ((tid & 63) == 0) {
            s_red[tid >> 6]       = wA;   // identical across lanes of the wave
            s_red[4 + (tid >> 6)] = wB;
        }
        if (tid == 0)   s_red[8] = vals[0];   // batch[p0]
        if (tid == 255) s_red[9] = vals[5];   // batch[p0 + WIN - 1]
        __syncthreads();
        const int KA = s_red[0] + s_red[1] + s_red[2] + s_red[3];
        const int KB = s_red[4] + s_red[5] + s_red[6] + s_red[7];
        start = p0 + KA;
        end   = p0 + KB;
        // bracket validation: everything left of window < g, right of window >= g+1
        const bool left_ok  = (p0 == 0) || (s_red[8] < g);
        const bool right_ok = (p0 + WIN == n) || (s_red[9] >= g + 1);
        window_ok = left_ok && right_ok;      // block-uniform
        __syncthreads();                      // s_red reused below (fallback)
    }
    if (!window_ok) {
        // ---- exact fallback: original 2-level strided search ----
        {
            const int pos1 = (int)(((long long)tid * n) >> 8);
            const int v = batch[pos1];
            const unsigned long long balA = __ballot(v < g);
            const unsigned long long balB = __ballot(v < g + 1);
            if ((tid & 63) == 0) {
                s_red[tid >> 6]       = __popcll(balA);
                s_red[4 + (tid >> 6)] = __popcll(balB);
            }
        }
        __syncthreads();
        const int KA = s_red[0] + s_red[1] + s_red[2] + s_red[3];
        const int KB = s_red[4] + s_red[5] + s_red[6] + s_red[7];
        const int loA = (KA == 0) ? 0 : (int)(((long long)(KA - 1) * n) >> 8) + 1;
        const int hiA = (KA == 256) ? n : (int)(((long long)KA * n) >> 8);
        const int loB = (KB == 0) ? 0 : (int)(((long long)(KB - 1) * n) >> 8) + 1;
        const int hiB = (KB == 256) ? n : (int)(((long long)KB * n) >> 8);
        __syncthreads();
        const int pA = loA + tid;
        const int pB = loB + tid;
        const int prA = (pA < hiA) ? (batch[pA] < g) : 0;
        const int prB = (pB < hiB) ? (batch[pB] < g + 1) : 0;
        const unsigned long long balA = __ballot(prA);
        const unsigned long long balB = __ballot(prB);
        if ((tid & 63) == 0) {
            s_red[tid >> 6]       = __popcll(balA);
            s_red[4 + (tid >> 6)] = __popcll(balB);
        }
        __syncthreads();
        start = loA + s_red[0] + s_red[1] + s_red[2] + s_red[3];
        end   = loB + s_red[4] + s_red[5] + s_red[6] + s_red[7];
        __syncthreads();
    }
    const int cnt = end - start;

    const int zi  = tid >> 4;
    const int shi = tid & 15;
    const int l   = (shi >= 9) ? 3 : (shi >= 4) ? 2 : (shi >= 1) ? 1 : 0;
    const int m   = shi - l * l;
    const int w   = 2 * l + 1;
    const int off = (l == 0) ? 0 : (l == 1) ? 160 : (l == 2) ? 640 : 1440;
    const int fbase = off + zi * 10 * w + m;   // out index for b=0; +b*w

    float acc[NB];
#pragma unroll
    for (int b = 0; b < NB; ++b) acc[b] = 0.0f;

    // c = SMOOTH_FINITE_C * e^2 * sqrt(NBASIS)
    const float CB = (float)(1.14136 * 7.389056098930650 * 3.1622776601683795);

    for (int nb0 = start; nb0 < end; nb0 += CHUNK) {
        const int nrem = min(CHUNK, end - nb0);
        __syncthreads();   // protects prev-iter LDS reads AND s_bcnt zeroing

        // ---- node-thread compute: pos loads first (consumed first), then x ----
        int   my_ib = 9;         // 9 = "no bucket" for non-node lanes
        int   my_rank = 0;
        float4 xr0, xr1, xr2, xr3;
        float sh[SHD];
        float bvA = 0.0f, bvB = 0.0f;
        if (tid < nrem) {
            const int node = nb0 + tid;
            const float px = pos[node * 3 + 0];
            const float py = pos[node * 3 + 1];
            const float pz = pos[node * 3 + 2];
            const float4* xp = (const float4*)(xin + (size_t)node * ZDIM);
            xr0 = xp[0]; xr1 = xp[1]; xr2 = xp[2]; xr3 = xp[3];   // in flight under sh compute
            const float r2 = px * px + py * py + pz * pz;
            const float rinv = rsqrtf(r2);
            const float X = px * rinv, Y = py * rinv, Z = pz * rinv;
            const float x2 = X * X, y2 = Y * Y, z2 = Z * Z;
            const float x2z2 = x2 + z2;
            const float s3  = 1.7320508075688772f;
            const float s5  = 2.2360679774997896f;
            const float s7  = 2.6457513110645907f;
            const float s15 = 3.8729833462074170f;
            const float c42_6  = 1.0801234497346435f;   // sqrt(42)/6
            const float c168_8 = 1.6201851746019651f;   // sqrt(168)/8
            const float sh2_0 = s15 * X * Z;
            const float sh2_1 = s15 * X * Y;
            const float sh2_2 = s5 * (y2 - 0.5f * x2z2);
            const float sh2_3 = s15 * Y * Z;
            const float sh2_4 = 0.5f * s15 * (z2 - x2);
            sh[0]  = 1.0f;
            sh[1]  = s3 * X;
            sh[2]  = s3 * Y;
            sh[3]  = s3 * Z;
            sh[4]  = sh2_0;
            sh[5]  = sh2_1;
            sh[6]  = sh2_2;
            sh[7]  = sh2_3;
            sh[8]  = sh2_4;
            sh[9]  = c42_6 * (sh2_0 * Z + sh2_4 * X);
            sh[10] = s7 * sh2_0 * Y;
            sh[11] = c168_8 * (4.0f * y2 - x2z2) * X;
            sh[12] = 0.5f * s7 * Y * (2.0f * y2 - 3.0f * x2z2);
            sh[13] = c168_8 * Z * (4.0f * y2 - x2z2);
            sh[14] = s7 * sh2_4 * Y;
            sh[15] = c42_6 * (sh2_4 * Z - sh2_0 * X);
            // radial basis: t = 1.1*d; active b in (t-2, t) -> at most {ib, ib+1}
            const float d = r2 * rinv;     // sqrt(r2)
            const float t = d * 1.1f;
            int ib = (int)floorf(t) - 1;
            ib = min(max(ib, 0), 8);
            {
                const float u1 = t - (float)ib, u2 = (float)(ib + 2) - t;
                if (u1 > 0.0f && u2 > 0.0f) bvA = CB * __expf(-1.0f / u1 - 1.0f / u2);
                const float v1 = t - (float)(ib + 1), v2 = (float)(ib + 3) - t;
                if (v1 > 0.0f && v2 > 0.0f) bvB = CB * __expf(-1.0f / v1 - 1.0f / v2);
            }
            my_ib = ib;
            my_rank = atomicAdd(&s_bcnt[ib], 1);   // ds_add_rtn: unique rank, arbitrary order (OK)
        }
        __syncthreads();   // bucket counts final

        // every thread: raw counts + padded bucket starts (compile-time indexed)
        int cw[9], cum[10];
        cum[0] = 0;
#pragma unroll
        for (int v = 0; v < 9; ++v) {
            cw[v] = s_bcnt[v];
            cum[v + 1] = cum[v] + ((cw[v] + 3) & ~3);
        }

        // ---- pad-only zeroing: <=3 pad columns per bucket, 48 floats each.
        // Lanes 0-15 of waves 0/1/2 zero one row-set each (2-way bank conflict max).
#pragma unroll
        for (int v = 0; v < 9; ++v) {
            const int base = cum[v] + cw[v];
            const int pads = cum[v + 1] - base;   // 0..3 (0 for empty buckets)
#pragma unroll
            for (int p = 0; p < 3; ++p) {
                if (p < pads) {
                    const int col = base + p;
                    if (tid < 16)                      s_xT [tid      ][col] = 0.0f;
                    else if (tid >= 64 && tid < 80)    s_shA[tid - 64 ][col] = 0.0f;
                    else if (tid >= 128 && tid < 144)  s_shB[tid - 128][col] = 0.0f;
                }
            }
        }

        // ---- stage into bucket-permuted columns ----
        if (tid < nrem) {
            int dest = my_rank;
#pragma unroll
            for (int v = 0; v < 9; ++v)
                dest += (v < my_ib) ? ((cw[v] + 3) & ~3) : 0;
#pragma unroll
            for (int k = 0; k < SHD; ++k) {
                s_shA[k][dest] = sh[k] * bvA;
                s_shB[k][dest] = sh[k] * bvB;
            }
            s_xT[ 0][dest] = xr0.x; s_xT[ 1][dest] = xr0.y;
            s_xT[ 2][dest] = xr0.z; s_xT[ 3][dest] = xr0.w;
            s_xT[ 4][dest] = xr1.x; s_xT[ 5][dest] = xr1.y;
            s_xT[ 6][dest] = xr1.z; s_xT[ 7][dest] = xr1.w;
            s_xT[ 8][dest] = xr2.x; s_xT[ 9][dest] = xr2.y;
            s_xT[10][dest] = xr2.z; s_xT[11][dest] = xr2.w;
            s_xT[12][dest] = xr3.x; s_xT[13][dest] = xr3.y;
            s_xT[14][dest] = xr3.z; s_xT[15][dest] = xr3.w;
        }
        __syncthreads();

        // counters re-zero for the next chunk: happens during the inner-loop
        // phase (s_bcnt not read here); next top-of-loop barrier publishes it.
        if (tid < 9) s_bcnt[tid] = 0;

        // ---- branch-free inner loop: 9 compile-time-ib bucket loops ----
#pragma unroll
        for (int v = 0; v < 9; ++v) {
#pragma unroll 2
            for (int c = cum[v]; c < cum[v + 1]; c += 4) {
                const float4 xv = *(const float4*)&s_xT[zi][c];
                const float4 sA = *(const float4*)&s_shA[shi][c];
                const float4 sB = *(const float4*)&s_shB[shi][c];
                acc[v] = fmaf(xv.w, sA.w, fmaf(xv.z, sA.z,
                         fmaf(xv.y, sA.y, fmaf(xv.x, sA.x, acc[v]))));
                acc[v + 1] = fmaf(xv.w, sB.w, fmaf(xv.z, sB.z,
                             fmaf(xv.y, sB.y, fmaf(xv.x, sB.x, acc[v + 1]))));
            }
        }
    }

    // mean + stage to LDS for coalesced output
    const float scale = 1.0f / (float)max(cnt, 1);
#pragma unroll
    for (int b = 0; b < NB; ++b) s_out[fbase + b * w] = acc[b] * scale;
    __syncthreads();
    float4* og4 = (float4*)(out + (size_t)g * FEAT);
    const float4* so4 = (const float4*)s_out;
    for (int i = tid; i < FEAT / 4; i += 256) og4[i] = so4[i];
}

extern "C" void kernel_launch(void* const* d_in, const int* in_sizes, int n_in,
                              void* d_out, int out_size, void* d_ws, size_t ws_size,
                              hipStream_t stream) {
    const float* x   = (const float*)d_in[0];
    const float* pos = (const float*)d_in[1];
    const int* batch = (const int*)d_in[2];
    float* out = (float*)d_out;
    const int n_nodes = in_sizes[2];

    hipLaunchKernelGGL(yfe_kernel, dim3(NGRAPHS), dim3(256), 0, stream,
                       x, pos, batch, out, n_nodes);
}